// Round 1
// baseline (3750.922 us; speedup 1.0000x reference)
//
#include <hip/hip_runtime.h>
#include <math.h>

// ---------------- problem constants ----------------
constexpr int NRNA = 40000;
constexpr int NDIS = 3000;
constexpr int NEDG = 600000;
constexpr int TREL = 10000;
constexpr int HIDC = 512;
constexpr int EXPD = 256;
constexpr int NEXP = 8;

// =====================================================================
// Generic tiled f32 GEMM:  C[M,N] = act(A[M,K] * B + bias)
// BT=true : B is [N,K] row-major (C = A * B^T)
// BT=false: B is [K,N] row-major (C = A * B)
// ACT: 0 none, 1 relu, 2 sigmoid.  Batched via blockIdx.z + strides.
// =====================================================================
template<bool BT, int ACT>
__global__ __launch_bounds__(256) void gemm_f32(
    const float* __restrict__ A, const float* __restrict__ B,
    const float* __restrict__ bias, float* __restrict__ C,
    int M, int N, int K, long sA, long sB, long sBias, long sC)
{
    constexpr int BM = 128, BN = 128, BK = 16;
    const int bz = blockIdx.z;
    const float* Ab = A + (long)bz * sA;
    const float* Bb = B + (long)bz * sB;
    float* Cb = C + (long)bz * sC;
    const float* biasb = bias ? (bias + (long)bz * sBias) : nullptr;
    const int row0 = blockIdx.y * BM, col0 = blockIdx.x * BN;

    __shared__ float As[BK][BM + 4];
    __shared__ float Bs[BK][BN + 4];

    const int tid = threadIdx.x;
    const int tx = tid & 15, ty = tid >> 4;
    float acc[8][8];
#pragma unroll
    for (int i = 0; i < 8; ++i)
#pragma unroll
        for (int j = 0; j < 8; ++j) acc[i][j] = 0.f;

    const int ar = tid >> 1, akq = (tid & 1) * 8;

    for (int k0 = 0; k0 < K; k0 += BK) {
        {   // stage A: 128 rows x 16 k
            int row = row0 + ar;
            float4 v0 = make_float4(0.f,0.f,0.f,0.f), v1 = v0;
            if (row < M) {
                const float* src = Ab + (long)row * K + k0 + akq;
                v0 = *(const float4*)src; v1 = *(const float4*)(src + 4);
            }
            As[akq+0][ar]=v0.x; As[akq+1][ar]=v0.y; As[akq+2][ar]=v0.z; As[akq+3][ar]=v0.w;
            As[akq+4][ar]=v1.x; As[akq+5][ar]=v1.y; As[akq+6][ar]=v1.z; As[akq+7][ar]=v1.w;
        }
        if (BT) {
            int col = col0 + ar;
            float4 v0 = make_float4(0.f,0.f,0.f,0.f), v1 = v0;
            if (col < N) {
                const float* src = Bb + (long)col * K + k0 + akq;
                v0 = *(const float4*)src; v1 = *(const float4*)(src + 4);
            }
            Bs[akq+0][ar]=v0.x; Bs[akq+1][ar]=v0.y; Bs[akq+2][ar]=v0.z; Bs[akq+3][ar]=v0.w;
            Bs[akq+4][ar]=v1.x; Bs[akq+5][ar]=v1.y; Bs[akq+6][ar]=v1.z; Bs[akq+7][ar]=v1.w;
        } else {
            int k = tid >> 4, n = (tid & 15) * 8;
            int col = col0 + n;
            float4 v0 = make_float4(0.f,0.f,0.f,0.f), v1 = v0;
            if (col < N) {
                const float* src = Bb + (long)(k0 + k) * N + col;
                v0 = *(const float4*)src; v1 = *(const float4*)(src + 4);
            }
            *(float4*)&Bs[k][n] = v0;
            *(float4*)&Bs[k][n + 4] = v1;
        }
        __syncthreads();
#pragma unroll
        for (int k = 0; k < BK; ++k) {
            float a[8], b[8];
            *(float4*)&a[0] = *(const float4*)&As[k][ty * 8];
            *(float4*)&a[4] = *(const float4*)&As[k][ty * 8 + 4];
            *(float4*)&b[0] = *(const float4*)&Bs[k][tx * 8];
            *(float4*)&b[4] = *(const float4*)&Bs[k][tx * 8 + 4];
#pragma unroll
            for (int i = 0; i < 8; ++i)
#pragma unroll
                for (int j = 0; j < 8; ++j)
                    acc[i][j] = fmaf(a[i], b[j], acc[i][j]);
        }
        __syncthreads();
    }
#pragma unroll
    for (int i = 0; i < 8; ++i) {
        int row = row0 + ty * 8 + i;
        if (row >= M) continue;
#pragma unroll
        for (int j = 0; j < 8; j += 4) {
            int col = col0 + tx * 8 + j;
            if (col < N) {   // all our N are multiples of 4
                float4 v;
                v.x = acc[i][j+0] + (biasb ? biasb[col+0] : 0.f);
                v.y = acc[i][j+1] + (biasb ? biasb[col+1] : 0.f);
                v.z = acc[i][j+2] + (biasb ? biasb[col+2] : 0.f);
                v.w = acc[i][j+3] + (biasb ? biasb[col+3] : 0.f);
                if (ACT == 1) {
                    v.x = fmaxf(v.x, 0.f); v.y = fmaxf(v.y, 0.f);
                    v.z = fmaxf(v.z, 0.f); v.w = fmaxf(v.w, 0.f);
                } else if (ACT == 2) {
                    v.x = 1.f / (1.f + __expf(-v.x));
                    v.y = 1.f / (1.f + __expf(-v.y));
                    v.z = 1.f / (1.f + __expf(-v.z));
                    v.w = 1.f / (1.f + __expf(-v.w));
                }
                *(float4*)(Cb + (long)row * N + col) = v;
            }
        }
    }
}

// =====================================================================
// per-(node,head) dot with attention vector: out[n,h] = sum_d x[n,h*64+d]*a[h,d]
// =====================================================================
__global__ void dot_heads(const float* __restrict__ x, const float* __restrict__ a,
                          float* __restrict__ out, int nodes)
{
    long g = (long)blockIdx.x * 256 + threadIdx.x;
    if (g >= (long)nodes * 8) return;
    int node = (int)(g >> 3), h = (int)(g & 7);
    const float* xp = x + (long)node * 512 + h * 64;
    const float* ap = a + h * 64;
    float s = 0.f;
#pragma unroll
    for (int d = 0; d < 64; d += 4) {
        float4 xv = *(const float4*)(xp + d);
        float4 av = *(const float4*)(ap + d);
        s += xv.x*av.x + xv.y*av.y + xv.z*av.z + xv.w*av.w;
    }
    out[g] = s;
}

// =====================================================================
// CSR build: histogram -> exclusive scan (single block) -> scatter
// =====================================================================
__global__ void hist_kernel(const int* __restrict__ dst, int* __restrict__ deg, int E)
{
    int g = blockIdx.x * 256 + threadIdx.x;
    if (g < E) atomicAdd(&deg[dst[g]], 1);
}

__global__ __launch_bounds__(1024) void exscan_kernel(const int* __restrict__ in,
                                                      int* __restrict__ out, int n)
{
    __shared__ int buf[1024];
    __shared__ int s_carry;
    const int tid = threadIdx.x;
    if (tid == 0) s_carry = 0;
    __syncthreads();
    for (int base = 0; base < n; base += 1024) {
        int v = (base + tid < n) ? in[base + tid] : 0;
        buf[tid] = v;
        __syncthreads();
        for (int off = 1; off < 1024; off <<= 1) {
            int t = (tid >= off) ? buf[tid - off] : 0;
            __syncthreads();
            buf[tid] += t;
            __syncthreads();
        }
        int carry = s_carry;
        if (base + tid < n) out[base + tid] = carry + buf[tid] - v;
        __syncthreads();
        if (tid == 1023) s_carry = carry + buf[1023];
        __syncthreads();
    }
    if (tid == 0) out[n] = s_carry;
}

__global__ void scatter_kernel(const int* __restrict__ src, const int* __restrict__ dst,
                               int* __restrict__ cur, int* __restrict__ csr_src, int E)
{
    int g = blockIdx.x * 256 + threadIdx.x;
    if (g < E) {
        int p = atomicAdd(&cur[dst[g]], 1);
        csr_src[p] = src[g];
    }
}

// =====================================================================
// HAN edge aggregation, one block per destination node.
// out[node, h*64+d] = relu( sum_e ex_e * x_src[src_e, h*64+d] / (den_h+1e-16) )
// ex_e = exp(lrelu(as_[src_e,h]+ad_[node,h]) - max_h)
// =====================================================================
__global__ __launch_bounds__(256) void han_aggregate(
    const int* __restrict__ offs, const int* __restrict__ csr_src,
    const float* __restrict__ as_, const float* __restrict__ ad_,
    const float* __restrict__ x_src, float* __restrict__ out)
{
    const int node = blockIdx.x;
    const int tid = threadIdx.x;
    const int e0 = offs[node], e1 = offs[node + 1];
    const int ne = e1 - e0;

    __shared__ float s_amax[8], s_den[8];
    __shared__ float s_ex[32 * 8];
    __shared__ int   s_srcs[32];
    __shared__ float s_red[256];

    const int myh = tid & 7;
    const float my_ad = ad_[node * 8 + myh];

    // pass 1: per-head max of leaky_relu(alpha)
    float mx = -3.0e38f;
    for (int i = tid; i < ne * 8; i += 256) {
        int e = e0 + (i >> 3);
        int src = csr_src[e];
        float al = as_[(long)src * 8 + myh] + my_ad;
        al = al >= 0.f ? al : 0.2f * al;
        mx = fmaxf(mx, al);
    }
    s_red[tid] = mx;
    __syncthreads();
    if (tid < 8) {
        float m = -3.0e38f;
        for (int j = tid; j < 256; j += 8) m = fmaxf(m, s_red[j]);
        s_amax[tid] = m;
    }
    __syncthreads();
    const float myamax = s_amax[myh];

    float acc0 = 0.f, acc1 = 0.f, dpart = 0.f;
    const int h0 = tid >> 6, h1 = (tid >> 6) + 4;

    for (int c0 = 0; c0 < ne; c0 += 32) {
        const int nc = min(32, ne - c0);
        if (tid < nc * 8) {
            int ec = tid >> 3;
            int src = csr_src[e0 + c0 + ec];
            if (myh == 0) s_srcs[ec] = src;
            float al = as_[(long)src * 8 + myh] + my_ad;
            al = al >= 0.f ? al : 0.2f * al;
            float ex = __expf(al - myamax);
            s_ex[ec * 8 + myh] = ex;
            dpart += ex;
        }
        __syncthreads();
        for (int j = 0; j < nc; ++j) {
            const float* x = x_src + (long)s_srcs[j] * 512;
            float w0 = s_ex[j * 8 + h0];
            float w1 = s_ex[j * 8 + h1];
            acc0 = fmaf(w0, x[tid], acc0);
            acc1 = fmaf(w1, x[tid + 256], acc1);
        }
        __syncthreads();
    }

    s_red[tid] = dpart;
    __syncthreads();
    if (tid < 8) {
        float s = 0.f;
        for (int j = tid; j < 256; j += 8) s += s_red[j];
        s_den[tid] = s;
    }
    __syncthreads();
    float d0 = s_den[h0] + 1e-16f, d1 = s_den[h1] + 1e-16f;
    out[(long)node * 512 + tid]       = fmaxf(acc0 / d0, 0.f);
    out[(long)node * 512 + tid + 256] = fmaxf(acc1 / d1, 0.f);
}

// =====================================================================
// d_global = mean over rows of h_dis   (two-stage, deterministic)
// =====================================================================
__global__ __launch_bounds__(512) void hdis_colsum_partial(const float* __restrict__ h_dis,
                                                           float* __restrict__ part)
{
    int c = blockIdx.x, d = threadIdx.x;        // 15 blocks x 200 rows
    int r0 = c * 200;
    float s = 0.f;
    for (int r = r0; r < r0 + 200; ++r) s += h_dis[(long)r * 512 + d];
    part[c * 512 + d] = s;
}
__global__ __launch_bounds__(512) void hdis_colsum_finish(const float* __restrict__ part,
                                                          float* __restrict__ dg)
{
    int d = threadIdx.x;
    float s = 0.f;
    for (int c = 0; c < 15; ++c) s += part[c * 512 + d];
    dg[d] = s * (1.f / NDIS);
}

// c_exp[e,d] = b_exp[e,d] + sum_f dg[f] * W_exp[e, 512+f, d]
__global__ void cexp_kernel(const float* __restrict__ dg, const float* __restrict__ W_exp,
                            const float* __restrict__ b_exp, float* __restrict__ c_exp)
{
    int e = blockIdx.x, d = threadIdx.x;
    const float* W = W_exp + (long)e * 1024 * 256 + 512 * 256 + d;
    float s = b_exp[e * 256 + d];
    for (int f = 0; f < 512; ++f) s = fmaf(dg[f], W[(long)f * 256], s);
    c_exp[e * 256 + d] = s;
}

// S[n,e] = sum_h h_rna[idx[n],h] * W_gate[n/T, h, e]
__global__ void scores_kernel(const float* __restrict__ h_rna, const float* __restrict__ W_gate,
                              const int* __restrict__ idx, float* __restrict__ S)
{
    long g = (long)blockIdx.x * 256 + threadIdx.x;    // n*8+e
    if (g >= (long)4 * TREL * 8) return;
    int n = (int)(g >> 3), e = (int)(g & 7);
    int r = n / TREL;
    const float* h = h_rna + (long)idx[n] * 512;
    const float* wg = W_gate + (long)r * 512 * 8 + e;
    float s = 0.f;
    for (int k = 0; k < 512; ++k) s = fmaf(h[k], wg[(long)k * 8], s);
    S[g] = s;
}

// =====================================================================
// Fused MoE: u[n,d] = sum_e S[n,e]*relu( h_rna[idx[n]] . W_exp[e][:512,d] + c_exp[e,d] )
// 64x64 tile, 8-expert loop, never materializes E.
// =====================================================================
__global__ __launch_bounds__(256) void moe_u_kernel(
    const float* __restrict__ h_rna, const float* __restrict__ W_exp,
    const float* __restrict__ c_exp, const float* __restrict__ S,
    const int* __restrict__ idx, float* __restrict__ u)
{
    const int col0 = blockIdx.x * 64;
    const int row0 = blockIdx.y * 64;
    __shared__ float As[16][68];
    __shared__ float Bs[16][68];
    __shared__ int s_idx[64];
    const int tid = threadIdx.x;
    if (tid < 64) s_idx[tid] = idx[row0 + tid];
    const int tx = tid & 15, ty = tid >> 4;
    float uacc[4][4];
#pragma unroll
    for (int i = 0; i < 4; ++i)
#pragma unroll
        for (int j = 0; j < 4; ++j) uacc[i][j] = 0.f;
    __syncthreads();

    const int alr = tid >> 2, alk = (tid & 3) * 4;
    const int blk_ = tid >> 4, bln = (tid & 15) * 4;

    for (int e = 0; e < NEXP; ++e) {
        float tacc[4][4];
#pragma unroll
        for (int i = 0; i < 4; ++i)
#pragma unroll
            for (int j = 0; j < 4; ++j) tacc[i][j] = 0.f;
        const float* We = W_exp + (long)e * 1024 * 256;
        for (int k0 = 0; k0 < 512; k0 += 16) {
            {
                float4 v = *(const float4*)(h_rna + (long)s_idx[alr] * 512 + k0 + alk);
                As[alk+0][alr]=v.x; As[alk+1][alr]=v.y; As[alk+2][alr]=v.z; As[alk+3][alr]=v.w;
            }
            {
                *(float4*)&Bs[blk_][bln] = *(const float4*)(We + (long)(k0 + blk_) * 256 + col0 + bln);
            }
            __syncthreads();
#pragma unroll
            for (int k = 0; k < 16; ++k) {
                float a[4], b[4];
                *(float4*)&a[0] = *(const float4*)&As[k][ty * 4];
                *(float4*)&b[0] = *(const float4*)&Bs[k][tx * 4];
#pragma unroll
                for (int i = 0; i < 4; ++i)
#pragma unroll
                    for (int j = 0; j < 4; ++j)
                        tacc[i][j] = fmaf(a[i], b[j], tacc[i][j]);
            }
            __syncthreads();
        }
#pragma unroll
        for (int i = 0; i < 4; ++i) {
            int row = row0 + ty * 4 + i;
            float s = S[(long)row * 8 + e];
#pragma unroll
            for (int j = 0; j < 4; ++j) {
                int col = col0 + tx * 4 + j;
                float v = tacc[i][j] + c_exp[e * 256 + col];
                uacc[i][j] = fmaf(s, fmaxf(v, 0.f), uacc[i][j]);
            }
        }
    }
#pragma unroll
    for (int i = 0; i < 4; ++i) {
        float4 v;
        v.x = uacc[i][0]; v.y = uacc[i][1]; v.z = uacc[i][2]; v.w = uacc[i][3];
        *(float4*)(u + (long)(row0 + ty * 4 + i) * 256 + col0 + tx * 4) = v;
    }
}

// U = mean_t u  (two stage)
__global__ void u_mean_partial(const float* __restrict__ u, float* __restrict__ part)
{
    int c = blockIdx.x, r = blockIdx.y, d = threadIdx.x;   // 32 x 4 blocks, 256 thr
    int t0 = c * 313, t1 = min(t0 + 313, TREL);
    const float* base = u + ((long)r * TREL) * 256 + d;
    float s = 0.f;
    for (int t = t0; t < t1; ++t) s += base[(long)t * 256];
    part[((long)r * 32 + c) * 256 + d] = s;
}
__global__ void u_mean_finish(const float* __restrict__ part, float* __restrict__ U)
{
    int r = blockIdx.x, d = threadIdx.x;
    float s = 0.f;
    for (int c = 0; c < 32; ++c) s += part[((long)r * 32 + c) * 256 + d];
    U[r * 256 + d] = s * (1.f / TREL);
}

// tiny 4-token cross attention, single block
__global__ __launch_bounds__(256) void cross_attn_kernel(
    const float* __restrict__ U, const float* __restrict__ in_w, const float* __restrict__ in_b,
    const float* __restrict__ out_w, const float* __restrict__ out_b, float* __restrict__ Up)
{
    __shared__ float sU[4 * 256];
    __shared__ float sqkv[4 * 768];
    __shared__ float sattn[128];
    __shared__ float so[4 * 256];
    const int tid = threadIdx.x;
    for (int i = tid; i < 1024; i += 256) sU[i] = U[i];
    __syncthreads();
    for (int o = tid; o < 3072; o += 256) {
        int row = o / 768, col = o % 768;
        const float* w = in_w + (long)col * 256;
        const float* uu = sU + row * 256;
        float s = in_b[col];
        for (int k = 0; k < 256; ++k) s = fmaf(uu[k], w[k], s);
        sqkv[o] = s;
    }
    __syncthreads();
    if (tid < 128) {
        int h = tid >> 4, t = (tid >> 2) & 3, s2 = tid & 3;
        const float* q = sqkv + t * 768 + h * 32;
        const float* kk = sqkv + s2 * 768 + 256 + h * 32;
        float s = 0.f;
        for (int d = 0; d < 32; ++d) s += q[d] * kk[d];
        sattn[tid] = s * 0.17677669529663687f;   // 1/sqrt(32)
    }
    __syncthreads();
    if (tid < 32) {
        int base = tid * 4;
        float a0 = sattn[base], a1 = sattn[base+1], a2 = sattn[base+2], a3 = sattn[base+3];
        float m = fmaxf(fmaxf(a0, a1), fmaxf(a2, a3));
        float e0 = __expf(a0 - m), e1 = __expf(a1 - m), e2 = __expf(a2 - m), e3 = __expf(a3 - m);
        float inv = 1.f / (e0 + e1 + e2 + e3);
        sattn[base] = e0 * inv; sattn[base+1] = e1 * inv;
        sattn[base+2] = e2 * inv; sattn[base+3] = e3 * inv;
    }
    __syncthreads();
    for (int o = tid; o < 1024; o += 256) {
        int t = o >> 8, hd = o & 255, h = hd >> 5, d = hd & 31;
        const float* a = sattn + (h * 4 + t) * 4;
        float s = 0.f;
        for (int s2 = 0; s2 < 4; ++s2) s += a[s2] * sqkv[s2 * 768 + 512 + h * 32 + d];
        so[t * 256 + hd] = s;
    }
    __syncthreads();
    for (int o = tid; o < 1024; o += 256) {
        int t = o >> 8, d = o & 255;
        const float* w = out_w + (long)d * 256;
        const float* ov = so + t * 256;
        float s = out_b[d];
        for (int k = 0; k < 256; ++k) s = fmaf(ov[k], w[k], s);
        Up[o] = s;
    }
}

// c_head[r,d] = b_head[r,d] + sum_c Up[r,c] * W_head[r, 256+c, d]
__global__ void chead_kernel(const float* __restrict__ Up, const float* __restrict__ W_head,
                             const float* __restrict__ b_head, float* __restrict__ c_head)
{
    int r = blockIdx.x, d = threadIdx.x;
    const float* W = W_head + (long)r * 512 * 256 + 256 * 256 + d;
    float s = b_head[r * 256 + d];
    for (int c = 0; c < 256; ++c) s = fmaf(Up[r * 256 + c], W[(long)c * 256], s);
    c_head[r * 256 + d] = s;
}

// =====================================================================
// host-side orchestration
// =====================================================================
extern "C" void kernel_launch(void* const* d_in, const int* in_sizes, int n_in,
                              void* d_out, int out_size, void* d_ws, size_t ws_size,
                              hipStream_t stream)
{
    (void)in_sizes; (void)n_in; (void)out_size;
    const float* x_rna    = (const float*)d_in[0];
    const float* x_dis    = (const float*)d_in[1];
    const float* Wd       = (const float*)d_in[2];
    const float* bd       = (const float*)d_in[3];
    const float* Wp_r     = (const float*)d_in[4];
    const float* bp_r     = (const float*)d_in[5];
    const float* Wp_d     = (const float*)d_in[6];
    const float* bp_d     = (const float*)d_in[7];
    const float* a_src_rd = (const float*)d_in[8];
    const float* a_dst_rd = (const float*)d_in[9];
    const float* a_src_dr = (const float*)d_in[10];
    const float* a_dst_dr = (const float*)d_in[11];
    // d_in[12..14] = kW, kb, qv : dead (semantic attention over M=1 is identity)
    const float* Wl       = (const float*)d_in[15];
    const float* bl       = (const float*)d_in[16];
    const float* W_exp    = (const float*)d_in[17];
    const float* b_exp    = (const float*)d_in[18];
    const float* W_gate   = (const float*)d_in[19];
    const float* W_head   = (const float*)d_in[20];
    const float* b_head   = (const float*)d_in[21];
    const float* in_w     = (const float*)d_in[22];
    const float* in_b     = (const float*)d_in[23];
    const float* out_w    = (const float*)d_in[24];
    const float* out_b    = (const float*)d_in[25];
    const float* Wdp      = (const float*)d_in[26];
    const float* bdp      = (const float*)d_in[27];
    const int* ei_rd_src  = (const int*)d_in[28];
    const int* ei_rd_dst  = (const int*)d_in[29];
    const int* ei_dr_src  = (const int*)d_in[30];
    const int* ei_dr_dst  = (const int*)d_in[31];
    const int* idx_rels   = (const int*)d_in[32];
    float* out = (float*)d_out;

    char* ws = (char*)d_ws;
    size_t off = 0;
    auto alloc = [&](size_t bytes) -> void* {
        off = (off + 255) & ~(size_t)255;
        void* p = ws + off;
        off += bytes;
        return p;
    };
    float* bufA    = (float*)alloc((size_t)NRNA * 512 * 4);   // hr0, later h_rna
    float* bufB    = (float*)alloc((size_t)NRNA * 512 * 4);   // out_rna, later p
    float* xd      = (float*)alloc((size_t)NDIS * 512 * 4);
    float* hd0     = (float*)alloc((size_t)NDIS * 512 * 4);   // later h_dis
    float* out_dis = (float*)alloc((size_t)NDIS * 512 * 4);
    float* u       = (float*)alloc((size_t)4 * TREL * 256 * 4);
    float* d_proj  = (float*)alloc((size_t)NDIS * 256 * 4);
    float* as_rd   = (float*)alloc((size_t)NRNA * 8 * 4);
    float* ad_rd   = (float*)alloc((size_t)NDIS * 8 * 4);
    float* as_dr   = (float*)alloc((size_t)NDIS * 8 * 4);
    float* ad_dr   = (float*)alloc((size_t)NRNA * 8 * 4);
    float* S       = (float*)alloc((size_t)4 * TREL * 8 * 4);
    float* dg_part = (float*)alloc((size_t)15 * 512 * 4);
    float* dg      = (float*)alloc((size_t)512 * 4);
    float* c_exp   = (float*)alloc((size_t)8 * 256 * 4);
    float* u_part  = (float*)alloc((size_t)4 * 32 * 256 * 4);
    float* U       = (float*)alloc((size_t)4 * 256 * 4);
    float* Up      = (float*)alloc((size_t)4 * 256 * 4);
    float* c_head  = (float*)alloc((size_t)4 * 256 * 4);
    int* deg_rd  = (int*)alloc((size_t)NDIS * 4);
    int* offs_rd = (int*)alloc((size_t)(NDIS + 1) * 4);
    int* cur_rd  = (int*)alloc((size_t)NDIS * 4);
    int* csr_rd  = (int*)alloc((size_t)NEDG * 4);
    int* deg_dr  = (int*)alloc((size_t)NRNA * 4);
    int* offs_dr = (int*)alloc((size_t)(NRNA + 1) * 4);
    int* cur_dr  = (int*)alloc((size_t)NRNA * 4);
    int* csr_dr  = (int*)alloc((size_t)NEDG * 4);
    if (off > ws_size) return;   // workspace too small -> fail loudly (poisoned out)

    float* hr0 = bufA;  float* h_rna = bufA;   // alias: hr0 dead before h_rna written
    float* out_rna = bufB; float* p = bufB;    // alias: out_rna dead before p written
    float* h_dis = hd0;                        // alias: hd0 dead before h_dis written

    const dim3 blk(256);

    // ---- projections ----
    gemm_f32<true,0><<<dim3(4, (NDIS + 127) / 128, 1), blk, 0, stream>>>(
        x_dis, Wd, bd, xd, NDIS, 512, 256, 0,0,0,0);
    gemm_f32<true,0><<<dim3(4, (NRNA + 127) / 128, 1), blk, 0, stream>>>(
        x_rna, Wp_r, bp_r, hr0, NRNA, 512, 512, 0,0,0,0);
    gemm_f32<true,0><<<dim3(4, (NDIS + 127) / 128, 1), blk, 0, stream>>>(
        xd, Wp_d, bp_d, hd0, NDIS, 512, 512, 0,0,0,0);

    // ---- attention dot products ----
    dot_heads<<<dim3((NRNA * 8) / 256), blk, 0, stream>>>(hr0, a_src_rd, as_rd, NRNA);
    dot_heads<<<dim3((NDIS * 8 + 255) / 256), blk, 0, stream>>>(hd0, a_dst_rd, ad_rd, NDIS);
    dot_heads<<<dim3((NDIS * 8 + 255) / 256), blk, 0, stream>>>(hd0, a_src_dr, as_dr, NDIS);
    dot_heads<<<dim3((NRNA * 8) / 256), blk, 0, stream>>>(hr0, a_dst_dr, ad_dr, NRNA);

    // ---- CSR build (both directions) ----
    hipMemsetAsync(deg_rd, 0, NDIS * 4, stream);
    hipMemsetAsync(deg_dr, 0, NRNA * 4, stream);
    hist_kernel<<<dim3((NEDG + 255) / 256), blk, 0, stream>>>(ei_rd_dst, deg_rd, NEDG);
    hist_kernel<<<dim3((NEDG + 255) / 256), blk, 0, stream>>>(ei_dr_dst, deg_dr, NEDG);
    exscan_kernel<<<1, 1024, 0, stream>>>(deg_rd, offs_rd, NDIS);
    exscan_kernel<<<1, 1024, 0, stream>>>(deg_dr, offs_dr, NRNA);
    hipMemcpyAsync(cur_rd, offs_rd, NDIS * 4, hipMemcpyDeviceToDevice, stream);
    hipMemcpyAsync(cur_dr, offs_dr, NRNA * 4, hipMemcpyDeviceToDevice, stream);
    scatter_kernel<<<dim3((NEDG + 255) / 256), blk, 0, stream>>>(ei_rd_src, ei_rd_dst, cur_rd, csr_rd, NEDG);
    scatter_kernel<<<dim3((NEDG + 255) / 256), blk, 0, stream>>>(ei_dr_src, ei_dr_dst, cur_dr, csr_dr, NEDG);

    // ---- HAN aggregation ----
    han_aggregate<<<dim3(NDIS), blk, 0, stream>>>(offs_rd, csr_rd, as_rd, ad_rd, hr0, out_dis);
    han_aggregate<<<dim3(NRNA), blk, 0, stream>>>(offs_dr, csr_dr, as_dr, ad_dr, hd0, out_rna);

    // ---- final shared linear (semantic attn over 1 metapath == identity) ----
    gemm_f32<true,0><<<dim3(4, (NRNA + 127) / 128, 1), blk, 0, stream>>>(
        out_rna, Wl, bl, h_rna, NRNA, 512, 512, 0,0,0,0);
    gemm_f32<true,0><<<dim3(4, (NDIS + 127) / 128, 1), blk, 0, stream>>>(
        out_dis, Wl, bl, h_dis, NDIS, 512, 512, 0,0,0,0);

    // ---- d_global and folded expert bias ----
    hdis_colsum_partial<<<dim3(15), dim3(512), 0, stream>>>(h_dis, dg_part);
    hdis_colsum_finish<<<dim3(1), dim3(512), 0, stream>>>(dg_part, dg);
    cexp_kernel<<<dim3(8), blk, 0, stream>>>(dg, W_exp, b_exp, c_exp);

    // ---- gate scores + fused MoE ----
    scores_kernel<<<dim3((4 * TREL * 8) / 256), blk, 0, stream>>>(h_rna, W_gate, idx_rels, S);
    moe_u_kernel<<<dim3(4, (4 * TREL) / 64), blk, 0, stream>>>(h_rna, W_exp, c_exp, S, idx_rels, u);

    // ---- U mean + cross attention + folded head bias ----
    u_mean_partial<<<dim3(32, 4), blk, 0, stream>>>(u, u_part);
    u_mean_finish<<<dim3(4), blk, 0, stream>>>(u_part, U);
    cross_attn_kernel<<<dim3(1), blk, 0, stream>>>(U, in_w, in_b, out_w, out_b, Up);
    chead_kernel<<<dim3(4), blk, 0, stream>>>(Up, W_head, b_head, c_head);

    // ---- per-relation heads: p = relu(u @ W_head[r][:256] + c_head[r]) ----
    gemm_f32<false,1><<<dim3(2, (TREL + 127) / 128, 4), blk, 0, stream>>>(
        u, W_head, c_head, p, TREL, 256, 256,
        (long)TREL * 256, (long)512 * 256, 256, (long)TREL * 256);

    // ---- disease projection ----
    gemm_f32<true,0><<<dim3(2, (NDIS + 127) / 128, 1), blk, 0, stream>>>(
        h_dis, Wdp, bdp, d_proj, NDIS, 256, 512, 0,0,0,0);

    // ---- final scores: sigmoid(p @ d_proj^T) -> d_out ----
    gemm_f32<true,2><<<dim3((NDIS + 127) / 128, (4 * TREL + 127) / 128, 1), blk, 0, stream>>>(
        p, d_proj, nullptr, out, 4 * TREL, NDIS, 256, 0,0,0,0);
}

// Round 2
// 1595.538 us; speedup vs baseline: 2.3509x; 2.3509x over previous
//
#include <hip/hip_runtime.h>
#include <math.h>

constexpr int NRNA = 40000;
constexpr int NDIS = 3000;
constexpr int NEDG = 600000;
constexpr int TREL = 10000;

typedef __attribute__((ext_vector_type(8))) short bh8;
typedef __attribute__((ext_vector_type(4))) float f32x4;

__device__ inline float bf2f(ushort x) {
    union { uint u; float f; } v; v.u = ((uint)x) << 16; return v.f;
}
__device__ inline ushort f2bf(float f) {
    union { float f; uint u; } v; v.f = f;
    uint u = v.u;
    uint r = (u + 0x7fffu + ((u >> 16) & 1u)) >> 16;
    return (ushort)r;
}
__device__ inline float bflo(uint w) { union { uint u; float f; } v; v.u = w << 16; return v.f; }
__device__ inline float bfhi(uint w) { union { uint u; float f; } v; v.u = w & 0xffff0000u; return v.f; }

// =====================================================================
// f32 -> bf16 conversion (vectorized, 4 elems/thread)
// =====================================================================
__global__ __launch_bounds__(256) void conv_bf16(const float* __restrict__ in,
                                                 ushort* __restrict__ out, long n)
{
    long g = ((long)blockIdx.x * 256 + threadIdx.x) * 4;
    if (g >= n) return;
    float4 v = *(const float4*)(in + g);
    ushort4 o;
    o.x = f2bf(v.x); o.y = f2bf(v.y); o.z = f2bf(v.z); o.w = f2bf(v.w);
    *(ushort4*)(out + g) = o;
}

// WexpT[e][d][f] = bf16(W_exp[e][f][d]);  e<8, f<512, d<256
__global__ __launch_bounds__(256) void transpose_wexp(const float* __restrict__ W,
                                                      ushort* __restrict__ out)
{
    long g = (long)blockIdx.x * 256 + threadIdx.x;     // 8*256*512 = 1048576
    int e = (int)(g >> 17), d = (int)((g >> 9) & 255), f = (int)(g & 511);
    out[g] = f2bf(W[(long)e * 262144 + (long)f * 256 + d]);
}

// WheadT[r][d][c] = bf16(W_head[r][c][d]);  r<4, c<256, d<256
__global__ __launch_bounds__(256) void transpose_whead(const float* __restrict__ W,
                                                       ushort* __restrict__ out)
{
    long g = (long)blockIdx.x * 256 + threadIdx.x;     // 4*256*256 = 262144
    int r = (int)(g >> 16), d = (int)((g >> 8) & 255), c = (int)(g & 255);
    out[g] = f2bf(W[(long)r * 131072 + (long)c * 256 + d]);
}

// =====================================================================
// MFMA bf16 GEMM: C[M,N] = act(A[M,K] * B^T + bias), B is [N,K] bf16.
// 128x128 tile, BK=64, 4 waves (2x2 of 64x64), 16x16x32 MFMA.
// idx: optional row gather for A. Cf (f32) and/or Cb (bf16) outputs.
// ACT: 0 none, 1 relu, 2 sigmoid. Batched via blockIdx.z.
// =====================================================================
template<int ACT>
__global__ __launch_bounds__(256) void gemm_mfma(
    const ushort* __restrict__ A, const ushort* __restrict__ B,
    const float* __restrict__ bias, float* __restrict__ Cf, ushort* __restrict__ Cb,
    const int* __restrict__ idx,
    int M, int N, int K, long sA, long sB, long sBias, long sC)
{
    __shared__ ushort As[128 * 72];      // pad 8 shorts -> 144B row stride (16B aligned)
    __shared__ ushort Bs[128 * 72];
    const int bz = blockIdx.z;
    const ushort* Ab = A + (long)bz * sA;
    const ushort* Bb = B + (long)bz * sB;
    const float* biasb = bias ? (bias + (long)bz * sBias) : nullptr;
    const int row0 = blockIdx.y * 128, col0 = blockIdx.x * 128;

    const int tid = threadIdx.x;
    const int wid = tid >> 6, lane = tid & 63;
    const int wr = wid >> 1, wc = wid & 1;

    f32x4 acc[4][4];
#pragma unroll
    for (int i = 0; i < 4; ++i)
#pragma unroll
        for (int n = 0; n < 4; ++n) acc[i][n] = (f32x4){0.f, 0.f, 0.f, 0.f};

    // staging: 2 threads per row, 32 shorts (64B) each
    const int ar = tid >> 1, ak = (tid & 1) * 32;
    const int arow = row0 + ar;
    const bool av = arow < M;
    const int asrc = av ? (idx ? idx[arow] : arow) : 0;
    const ushort* aptr = Ab + (long)asrc * K + ak;
    const int bcol = col0 + ar;
    const bool bv = bcol < N;
    const ushort* bptr = Bb + (long)(bv ? bcol : 0) * K + ak;
    ushort* da = As + ar * 72 + ak;
    ushort* db = Bs + ar * 72 + ak;

    const ushort* pa = As + (wr * 64 + (lane & 15)) * 72 + (lane >> 4) * 8;
    const ushort* pb = Bs + (wc * 64 + (lane & 15)) * 72 + (lane >> 4) * 8;

    const uint4 z4 = make_uint4(0, 0, 0, 0);
    for (int k0 = 0; k0 < K; k0 += 64) {
        if (av) {
            const uint4* s = (const uint4*)(aptr + k0);
            uint4 v0 = s[0], v1 = s[1], v2 = s[2], v3 = s[3];
            *(uint4*)(da) = v0; *(uint4*)(da + 8) = v1;
            *(uint4*)(da + 16) = v2; *(uint4*)(da + 24) = v3;
        } else {
            *(uint4*)(da) = z4; *(uint4*)(da + 8) = z4;
            *(uint4*)(da + 16) = z4; *(uint4*)(da + 24) = z4;
        }
        if (bv) {
            const uint4* s = (const uint4*)(bptr + k0);
            uint4 v0 = s[0], v1 = s[1], v2 = s[2], v3 = s[3];
            *(uint4*)(db) = v0; *(uint4*)(db + 8) = v1;
            *(uint4*)(db + 16) = v2; *(uint4*)(db + 24) = v3;
        } else {
            *(uint4*)(db) = z4; *(uint4*)(db + 8) = z4;
            *(uint4*)(db + 16) = z4; *(uint4*)(db + 24) = z4;
        }
        __syncthreads();
#pragma unroll
        for (int kk = 0; kk < 2; ++kk) {
            bh8 af[4], bf[4];
#pragma unroll
            for (int i = 0; i < 4; ++i) af[i] = *(const bh8*)(pa + i * 16 * 72 + kk * 32);
#pragma unroll
            for (int n = 0; n < 4; ++n) bf[n] = *(const bh8*)(pb + n * 16 * 72 + kk * 32);
#pragma unroll
            for (int i = 0; i < 4; ++i)
#pragma unroll
                for (int n = 0; n < 4; ++n)
                    acc[i][n] = __builtin_amdgcn_mfma_f32_16x16x32_bf16(af[i], bf[n], acc[i][n], 0, 0, 0);
        }
        __syncthreads();
    }

#pragma unroll
    for (int i = 0; i < 4; ++i) {
#pragma unroll
        for (int r = 0; r < 4; ++r) {
            int m = row0 + wr * 64 + i * 16 + (lane >> 4) * 4 + r;
            if (m >= M) continue;
#pragma unroll
            for (int n = 0; n < 4; ++n) {
                int nn = col0 + wc * 64 + n * 16 + (lane & 15);
                if (nn >= N) continue;
                float v = acc[i][n][r] + (biasb ? biasb[nn] : 0.f);
                if (ACT == 1) v = fmaxf(v, 0.f);
                else if (ACT == 2) v = 1.f / (1.f + __expf(-v));
                long o = (long)bz * sC + (long)m * N + nn;
                if (Cf) Cf[o] = v;
                if (Cb) Cb[o] = f2bf(v);
            }
        }
    }
}

// =====================================================================
// Fused MoE with MFMA: u[n,d] = sum_e S[n,e]*relu( h[idx[n]] . WexpT[e][d] + c_exp[e,d] )
// A gathered rows of h (bf16 [40000][512]); WexpT bf16 [8][256][512]. u bf16 out.
// =====================================================================
__global__ __launch_bounds__(256) void moe_mfma(
    const ushort* __restrict__ h, const ushort* __restrict__ WexpT,
    const float* __restrict__ c_exp, const float* __restrict__ S,
    const int* __restrict__ idx, ushort* __restrict__ u)
{
    __shared__ ushort As[128 * 72];
    __shared__ ushort Bs[128 * 72];
    __shared__ float sS[128 * 8];
    __shared__ float sC[8 * 128];
    const int row0 = blockIdx.y * 128, col0 = blockIdx.x * 128;
    const int tid = threadIdx.x;
    const int wid = tid >> 6, lane = tid & 63;
    const int wr = wid >> 1, wc = wid & 1;
    constexpr int M = 4 * TREL;

    for (int i = tid; i < 1024; i += 256) {
        int rr = i >> 3, e = i & 7;
        sS[i] = (row0 + rr < M) ? S[(long)(row0 + rr) * 8 + e] : 0.f;
        int ee = i >> 7, cc = i & 127;
        sC[i] = c_exp[ee * 256 + col0 + cc];
    }

    const int ar = tid >> 1, ak = (tid & 1) * 32;
    const int arow = row0 + ar;
    const bool av = arow < M;
    const int asrc = av ? idx[arow] : 0;
    const ushort* aptr = h + (long)asrc * 512 + ak;
    const ushort* bbase = WexpT + (long)(col0 + ar) * 512 + ak;
    ushort* da = As + ar * 72 + ak;
    ushort* db = Bs + ar * 72 + ak;
    const ushort* pa = As + (wr * 64 + (lane & 15)) * 72 + (lane >> 4) * 8;
    const ushort* pb = Bs + (wc * 64 + (lane & 15)) * 72 + (lane >> 4) * 8;

    f32x4 uacc[4][4];
#pragma unroll
    for (int i = 0; i < 4; ++i)
#pragma unroll
        for (int n = 0; n < 4; ++n) uacc[i][n] = (f32x4){0.f, 0.f, 0.f, 0.f};
    __syncthreads();

    const uint4 z4 = make_uint4(0, 0, 0, 0);
    for (int e = 0; e < 8; ++e) {
        f32x4 acc[4][4];
#pragma unroll
        for (int i = 0; i < 4; ++i)
#pragma unroll
            for (int n = 0; n < 4; ++n) acc[i][n] = (f32x4){0.f, 0.f, 0.f, 0.f};
        const ushort* be = bbase + (long)e * 131072;
        for (int k0 = 0; k0 < 512; k0 += 64) {
            if (av) {
                const uint4* s = (const uint4*)(aptr + k0);
                uint4 v0 = s[0], v1 = s[1], v2 = s[2], v3 = s[3];
                *(uint4*)(da) = v0; *(uint4*)(da + 8) = v1;
                *(uint4*)(da + 16) = v2; *(uint4*)(da + 24) = v3;
            } else {
                *(uint4*)(da) = z4; *(uint4*)(da + 8) = z4;
                *(uint4*)(da + 16) = z4; *(uint4*)(da + 24) = z4;
            }
            {
                const uint4* s = (const uint4*)(be + k0);
                uint4 v0 = s[0], v1 = s[1], v2 = s[2], v3 = s[3];
                *(uint4*)(db) = v0; *(uint4*)(db + 8) = v1;
                *(uint4*)(db + 16) = v2; *(uint4*)(db + 24) = v3;
            }
            __syncthreads();
#pragma unroll
            for (int kk = 0; kk < 2; ++kk) {
                bh8 af[4], bf[4];
#pragma unroll
                for (int i = 0; i < 4; ++i) af[i] = *(const bh8*)(pa + i * 16 * 72 + kk * 32);
#pragma unroll
                for (int n = 0; n < 4; ++n) bf[n] = *(const bh8*)(pb + n * 16 * 72 + kk * 32);
#pragma unroll
                for (int i = 0; i < 4; ++i)
#pragma unroll
                    for (int n = 0; n < 4; ++n)
                        acc[i][n] = __builtin_amdgcn_mfma_f32_16x16x32_bf16(af[i], bf[n], acc[i][n], 0, 0, 0);
            }
            __syncthreads();
        }
#pragma unroll
        for (int i = 0; i < 4; ++i) {
            int rl = wr * 64 + i * 16 + (lane >> 4) * 4;
#pragma unroll
            for (int n = 0; n < 4; ++n) {
                int cl = wc * 64 + n * 16 + (lane & 15);
                float c = sC[e * 128 + cl];
#pragma unroll
                for (int r = 0; r < 4; ++r) {
                    float s = sS[(rl + r) * 8 + e];
                    float v = acc[i][n][r] + c;
                    uacc[i][n][r] = fmaf(s, fmaxf(v, 0.f), uacc[i][n][r]);
                }
            }
        }
    }

#pragma unroll
    for (int i = 0; i < 4; ++i) {
#pragma unroll
        for (int r = 0; r < 4; ++r) {
            int m = row0 + wr * 64 + i * 16 + (lane >> 4) * 4 + r;
            if (m >= M) continue;
#pragma unroll
            for (int n = 0; n < 4; ++n) {
                int nn = col0 + wc * 64 + n * 16 + (lane & 15);
                u[(long)m * 256 + nn] = f2bf(uacc[i][n][r]);
            }
        }
    }
}

// =====================================================================
// per-(node,head) dot (bf16 x): out[n,h] = sum_d x[n,h*64+d]*a[h,d]
// =====================================================================
__global__ void dot_heads_bf(const ushort* __restrict__ x, const float* __restrict__ a,
                             float* __restrict__ out, int nodes)
{
    long g = (long)blockIdx.x * 256 + threadIdx.x;
    if (g >= (long)nodes * 8) return;
    int node = (int)(g >> 3), h = (int)(g & 7);
    const ushort* xp = x + (long)node * 512 + h * 64;
    const float* ap = a + h * 64;
    float s = 0.f;
#pragma unroll
    for (int d = 0; d < 64; d += 8) {
        uint4 xv = *(const uint4*)(xp + d);
        float4 a0 = *(const float4*)(ap + d);
        float4 a1 = *(const float4*)(ap + d + 4);
        s += bflo(xv.x) * a0.x + bfhi(xv.x) * a0.y + bflo(xv.y) * a0.z + bfhi(xv.y) * a0.w;
        s += bflo(xv.z) * a1.x + bfhi(xv.z) * a1.y + bflo(xv.w) * a1.z + bfhi(xv.w) * a1.w;
    }
    out[g] = s;
}

// =====================================================================
// CSR build
// =====================================================================
__global__ void hist_kernel(const int* __restrict__ dst, int* __restrict__ deg, int E)
{
    int g = blockIdx.x * 256 + threadIdx.x;
    if (g < E) atomicAdd(&deg[dst[g]], 1);
}

__global__ __launch_bounds__(1024) void exscan_kernel(const int* __restrict__ in,
                                                      int* __restrict__ out, int n)
{
    __shared__ int wsum[16];
    __shared__ int s_carry;
    const int tid = threadIdx.x, lane = tid & 63, wid = tid >> 6;
    if (tid == 0) s_carry = 0;
    __syncthreads();
    for (int base = 0; base < n; base += 1024) {
        int v = (base + tid < n) ? in[base + tid] : 0;
        int s = v;
#pragma unroll
        for (int off = 1; off < 64; off <<= 1) {
            int t = __shfl_up(s, off, 64);
            if (lane >= off) s += t;
        }
        if (lane == 63) wsum[wid] = s;
        __syncthreads();
        if (wid == 0) {
            int w = (lane < 16) ? wsum[lane] : 0;
#pragma unroll
            for (int off = 1; off < 16; off <<= 1) {
                int t = __shfl_up(w, off, 64);
                if (lane >= off) w += t;
            }
            if (lane < 16) wsum[lane] = w;   // inclusive wave sums
        }
        __syncthreads();
        int wadd = (wid == 0) ? 0 : wsum[wid - 1];
        int carry = s_carry;
        if (base + tid < n) out[base + tid] = carry + wadd + s - v;
        __syncthreads();
        if (tid == 1023) s_carry = carry + wsum[15];
        __syncthreads();
    }
    if (threadIdx.x == 0) out[n] = s_carry;
}

__global__ void scatter_kernel(const int* __restrict__ src, const int* __restrict__ dst,
                               int* __restrict__ cur, int* __restrict__ csr_src, int E)
{
    int g = blockIdx.x * 256 + threadIdx.x;
    if (g < E) {
        int p = atomicAdd(&cur[dst[g]], 1);
        csr_src[p] = src[g];
    }
}

// =====================================================================
// HAN edge aggregation, bf16 gather + bf16 out
// =====================================================================
__global__ __launch_bounds__(256) void han_aggregate(
    const int* __restrict__ offs, const int* __restrict__ csr_src,
    const float* __restrict__ as_, const float* __restrict__ ad_,
    const ushort* __restrict__ x_src, ushort* __restrict__ out)
{
    const int node = blockIdx.x;
    const int tid = threadIdx.x;
    const int e0 = offs[node], e1 = offs[node + 1];
    const int ne = e1 - e0;

    __shared__ float s_amax[8], s_den[8];
    __shared__ float s_ex[32 * 8];
    __shared__ int   s_srcs[32];
    __shared__ float s_red[256];

    const int myh = tid & 7;
    const float my_ad = ad_[node * 8 + myh];

    float mx = -3.0e38f;
    for (int i = tid; i < ne * 8; i += 256) {
        int e = e0 + (i >> 3);
        int src = csr_src[e];
        float al = as_[(long)src * 8 + myh] + my_ad;
        al = al >= 0.f ? al : 0.2f * al;
        mx = fmaxf(mx, al);
    }
    s_red[tid] = mx;
    __syncthreads();
    if (tid < 8) {
        float m = -3.0e38f;
        for (int j = tid; j < 256; j += 8) m = fmaxf(m, s_red[j]);
        s_amax[tid] = m;
    }
    __syncthreads();
    const float myamax = s_amax[myh];

    float acc0 = 0.f, acc1 = 0.f, dpart = 0.f;
    const int h0 = tid >> 6, h1 = (tid >> 6) + 4;

    for (int c0 = 0; c0 < ne; c0 += 32) {
        const int nc = min(32, ne - c0);
        if (tid < nc * 8) {
            int ec = tid >> 3;
            int src = csr_src[e0 + c0 + ec];
            if (myh == 0) s_srcs[ec] = src;
            float al = as_[(long)src * 8 + myh] + my_ad;
            al = al >= 0.f ? al : 0.2f * al;
            float ex = __expf(al - myamax);
            s_ex[ec * 8 + myh] = ex;
            dpart += ex;
        }
        __syncthreads();
        for (int j = 0; j < nc; ++j) {
            const ushort* x = x_src + (long)s_srcs[j] * 512;
            float w0 = s_ex[j * 8 + h0];
            float w1 = s_ex[j * 8 + h1];
            acc0 = fmaf(w0, bf2f(x[tid]), acc0);
            acc1 = fmaf(w1, bf2f(x[tid + 256]), acc1);
        }
        __syncthreads();
    }

    s_red[tid] = dpart;
    __syncthreads();
    if (tid < 8) {
        float s = 0.f;
        for (int j = tid; j < 256; j += 8) s += s_red[j];
        s_den[tid] = s;
    }
    __syncthreads();
    float d0 = s_den[h0] + 1e-16f, d1 = s_den[h1] + 1e-16f;
    out[(long)node * 512 + tid]       = f2bf(fmaxf(acc0 / d0, 0.f));
    out[(long)node * 512 + tid + 256] = f2bf(fmaxf(acc1 / d1, 0.f));
}

// =====================================================================
// d_global from f32 h_dis; folded expert bias
// =====================================================================
__global__ __launch_bounds__(512) void hdis_colsum_partial(const float* __restrict__ h_dis,
                                                           float* __restrict__ part)
{
    int c = blockIdx.x, d = threadIdx.x;
    int r0 = c * 200;
    float s = 0.f;
    for (int r = r0; r < r0 + 200; ++r) s += h_dis[(long)r * 512 + d];
    part[c * 512 + d] = s;
}
__global__ __launch_bounds__(512) void hdis_colsum_finish(const float* __restrict__ part,
                                                          float* __restrict__ dg)
{
    int d = threadIdx.x;
    float s = 0.f;
    for (int c = 0; c < 15; ++c) s += part[c * 512 + d];
    dg[d] = s * (1.f / NDIS);
}

__global__ void cexp_kernel(const float* __restrict__ dg, const float* __restrict__ W_exp,
                            const float* __restrict__ b_exp, float* __restrict__ c_exp)
{
    int e = blockIdx.x, d = threadIdx.x;
    const float* W = W_exp + (long)e * 1024 * 256 + 512 * 256 + d;
    float s = b_exp[e * 256 + d];
    for (int f = 0; f < 512; ++f) s = fmaf(dg[f], W[(long)f * 256], s);
    c_exp[e * 256 + d] = s;
}

// S[n,e] from bf16 h_rna
__global__ void scores_bf(const ushort* __restrict__ h, const float* __restrict__ Wg,
                          const int* __restrict__ idx, float* __restrict__ S)
{
    long g = (long)blockIdx.x * 256 + threadIdx.x;
    if (g >= (long)4 * TREL * 8) return;
    int n = (int)(g >> 3), e = (int)(g & 7);
    int r = n / TREL;
    const ushort* hp = h + (long)idx[n] * 512;
    const float* wg = Wg + (long)r * 4096 + e;
    float s = 0.f;
    for (int k = 0; k < 512; ++k) s = fmaf(bf2f(hp[k]), wg[(long)k * 8], s);
    S[g] = s;
}

// U = mean_t u (bf16 in)
__global__ void u_mean_partial(const ushort* __restrict__ u, float* __restrict__ part)
{
    int c = blockIdx.x, r = blockIdx.y, d = threadIdx.x;
    int t0 = c * 313, t1 = min(t0 + 313, TREL);
    const ushort* base = u + ((long)r * TREL) * 256 + d;
    float s = 0.f;
    for (int t = t0; t < t1; ++t) s += bf2f(base[(long)t * 256]);
    part[((long)r * 32 + c) * 256 + d] = s;
}
__global__ void u_mean_finish(const float* __restrict__ part, float* __restrict__ U)
{
    int r = blockIdx.x, d = threadIdx.x;
    float s = 0.f;
    for (int c = 0; c < 32; ++c) s += part[((long)r * 32 + c) * 256 + d];
    U[r * 256 + d] = s * (1.f / TREL);
}

// tiny 4-token cross attention
__global__ __launch_bounds__(256) void cross_attn_kernel(
    const float* __restrict__ U, const float* __restrict__ in_w, const float* __restrict__ in_b,
    const float* __restrict__ out_w, const float* __restrict__ out_b, float* __restrict__ Up)
{
    __shared__ float sU[4 * 256];
    __shared__ float sqkv[4 * 768];
    __shared__ float sattn[128];
    __shared__ float so[4 * 256];
    const int tid = threadIdx.x;
    for (int i = tid; i < 1024; i += 256) sU[i] = U[i];
    __syncthreads();
    for (int o = tid; o < 3072; o += 256) {
        int row = o / 768, col = o % 768;
        const float* w = in_w + (long)col * 256;
        const float* uu = sU + row * 256;
        float s = in_b[col];
        for (int k = 0; k < 256; ++k) s = fmaf(uu[k], w[k], s);
        sqkv[o] = s;
    }
    __syncthreads();
    if (tid < 128) {
        int h = tid >> 4, t = (tid >> 2) & 3, s2 = tid & 3;
        const float* q = sqkv + t * 768 + h * 32;
        const float* kk = sqkv + s2 * 768 + 256 + h * 32;
        float s = 0.f;
        for (int d = 0; d < 32; ++d) s += q[d] * kk[d];
        sattn[tid] = s * 0.17677669529663687f;
    }
    __syncthreads();
    if (tid < 32) {
        int base = tid * 4;
        float a0 = sattn[base], a1 = sattn[base+1], a2 = sattn[base+2], a3 = sattn[base+3];
        float m = fmaxf(fmaxf(a0, a1), fmaxf(a2, a3));
        float e0 = __expf(a0 - m), e1 = __expf(a1 - m), e2 = __expf(a2 - m), e3 = __expf(a3 - m);
        float inv = 1.f / (e0 + e1 + e2 + e3);
        sattn[base] = e0 * inv; sattn[base+1] = e1 * inv;
        sattn[base+2] = e2 * inv; sattn[base+3] = e3 * inv;
    }
    __syncthreads();
    for (int o = tid; o < 1024; o += 256) {
        int t = o >> 8, hd = o & 255, h = hd >> 5, d = hd & 31;
        const float* a = sattn + (h * 4 + t) * 4;
        float s = 0.f;
        for (int s2 = 0; s2 < 4; ++s2) s += a[s2] * sqkv[s2 * 768 + 512 + h * 32 + d];
        so[t * 256 + hd] = s;
    }
    __syncthreads();
    for (int o = tid; o < 1024; o += 256) {
        int t = o >> 8, d = o & 255;
        const float* w = out_w + (long)d * 256;
        const float* ov = so + t * 256;
        float s = out_b[d];
        for (int k = 0; k < 256; ++k) s = fmaf(ov[k], w[k], s);
        Up[o] = s;
    }
}

__global__ void chead_kernel(const float* __restrict__ Up, const float* __restrict__ W_head,
                             const float* __restrict__ b_head, float* __restrict__ c_head)
{
    int r = blockIdx.x, d = threadIdx.x;
    const float* W = W_head + (long)r * 512 * 256 + 256 * 256 + d;
    float s = b_head[r * 256 + d];
    for (int c = 0; c < 256; ++c) s = fmaf(Up[r * 256 + c], W[(long)c * 256], s);
    c_head[r * 256 + d] = s;
}

// =====================================================================
// host-side orchestration
// =====================================================================
extern "C" void kernel_launch(void* const* d_in, const int* in_sizes, int n_in,
                              void* d_out, int out_size, void* d_ws, size_t ws_size,
                              hipStream_t stream)
{
    (void)in_sizes; (void)n_in; (void)out_size;
    const float* x_rna    = (const float*)d_in[0];
    const float* x_dis    = (const float*)d_in[1];
    const float* Wd       = (const float*)d_in[2];
    const float* bd       = (const float*)d_in[3];
    const float* Wp_r     = (const float*)d_in[4];
    const float* bp_r     = (const float*)d_in[5];
    const float* Wp_d     = (const float*)d_in[6];
    const float* bp_d     = (const float*)d_in[7];
    const float* a_src_rd = (const float*)d_in[8];
    const float* a_dst_rd = (const float*)d_in[9];
    const float* a_src_dr = (const float*)d_in[10];
    const float* a_dst_dr = (const float*)d_in[11];
    // d_in[12..14] dead (semantic attn over one metapath == identity)
    const float* Wl       = (const float*)d_in[15];
    const float* bl       = (const float*)d_in[16];
    const float* W_exp    = (const float*)d_in[17];
    const float* b_exp    = (const float*)d_in[18];
    const float* W_gate   = (const float*)d_in[19];
    const float* W_head   = (const float*)d_in[20];
    const float* b_head   = (const float*)d_in[21];
    const float* in_w     = (const float*)d_in[22];
    const float* in_b     = (const float*)d_in[23];
    const float* out_w    = (const float*)d_in[24];
    const float* out_b    = (const float*)d_in[25];
    const float* Wdp      = (const float*)d_in[26];
    const float* bdp      = (const float*)d_in[27];
    const int* ei_rd_src  = (const int*)d_in[28];
    const int* ei_rd_dst  = (const int*)d_in[29];
    const int* ei_dr_src  = (const int*)d_in[30];
    const int* ei_dr_dst  = (const int*)d_in[31];
    const int* idx_rels   = (const int*)d_in[32];
    float* out = (float*)d_out;

    char* ws = (char*)d_ws;
    size_t off = 0;
    auto alloc = [&](size_t bytes) -> void* {
        off = (off + 255) & ~(size_t)255;
        void* p = ws + off;
        off += bytes;
        return p;
    };
    // big bf16 buffers (with aliasing)
    ushort* xrb      = (ushort*)alloc((size_t)NRNA * 512 * 2);  // x_rna bf16; later out_rna
    ushort* hr0b     = (ushort*)alloc((size_t)NRNA * 512 * 2);  // hr0 bf16; later h_rna
    ushort* u_bf     = (ushort*)alloc((size_t)4 * TREL * 256 * 2);
    ushort* p_bf     = (ushort*)alloc((size_t)4 * TREL * 256 * 2);
    ushort* xdb      = (ushort*)alloc((size_t)NDIS * 256 * 2);
    ushort* xd_bf    = (ushort*)alloc((size_t)NDIS * 512 * 2);
    ushort* hd0b     = (ushort*)alloc((size_t)NDIS * 512 * 2);
    ushort* outdis_b = (ushort*)alloc((size_t)NDIS * 512 * 2);
    ushort* hdis_b   = (ushort*)alloc((size_t)NDIS * 512 * 2);
    ushort* dproj_b  = (ushort*)alloc((size_t)NDIS * 256 * 2);
    float*  hdis_f   = (float*)alloc((size_t)NDIS * 512 * 4);
    // weights bf16
    ushort* Wdb    = (ushort*)alloc((size_t)512 * 256 * 2);
    ushort* Wprb   = (ushort*)alloc((size_t)512 * 512 * 2);
    ushort* Wpdb   = (ushort*)alloc((size_t)512 * 512 * 2);
    ushort* Wlb    = (ushort*)alloc((size_t)512 * 512 * 2);
    ushort* Wdpb   = (ushort*)alloc((size_t)256 * 512 * 2);
    ushort* WexpT  = (ushort*)alloc((size_t)8 * 256 * 512 * 2);
    ushort* WheadT = (ushort*)alloc((size_t)4 * 256 * 256 * 2);
    // f32 small
    float* as_rd   = (float*)alloc((size_t)NRNA * 8 * 4);
    float* ad_rd   = (float*)alloc((size_t)NDIS * 8 * 4);
    float* as_dr   = (float*)alloc((size_t)NDIS * 8 * 4);
    float* ad_dr   = (float*)alloc((size_t)NRNA * 8 * 4);
    float* S       = (float*)alloc((size_t)4 * TREL * 8 * 4);
    float* dg_part = (float*)alloc((size_t)15 * 512 * 4);
    float* dg      = (float*)alloc((size_t)512 * 4);
    float* c_exp   = (float*)alloc((size_t)8 * 256 * 4);
    float* u_part  = (float*)alloc((size_t)4 * 32 * 256 * 4);
    float* U       = (float*)alloc((size_t)4 * 256 * 4);
    float* Up      = (float*)alloc((size_t)4 * 256 * 4);
    float* c_head  = (float*)alloc((size_t)4 * 256 * 4);
    // CSR
    int* deg_rd  = (int*)alloc((size_t)NDIS * 4);
    int* offs_rd = (int*)alloc((size_t)(NDIS + 1) * 4);
    int* cur_rd  = (int*)alloc((size_t)NDIS * 4);
    int* csr_rd  = (int*)alloc((size_t)NEDG * 4);
    int* deg_dr  = (int*)alloc((size_t)NRNA * 4);
    int* offs_dr = (int*)alloc((size_t)(NRNA + 1) * 4);
    int* cur_dr  = (int*)alloc((size_t)NRNA * 4);
    int* csr_dr  = (int*)alloc((size_t)NEDG * 4);
    if (off > ws_size) return;

    ushort* outrna_b = xrb;    // alias: x_rna bf16 dead after hr0 GEMM
    ushort* hrna_b   = hr0b;   // alias: hr0 dead after han + dot_heads

    const dim3 blk(256);

    // ---- conversions ----
    conv_bf16<<<dim3(20000), blk, 0, stream>>>(x_rna, xrb, (long)NRNA * 512);
    conv_bf16<<<dim3(750),   blk, 0, stream>>>(x_dis, xdb, (long)NDIS * 256);
    conv_bf16<<<dim3(128),   blk, 0, stream>>>(Wd,   Wdb,  512 * 256);
    conv_bf16<<<dim3(256),   blk, 0, stream>>>(Wp_r, Wprb, 512 * 512);
    conv_bf16<<<dim3(256),   blk, 0, stream>>>(Wp_d, Wpdb, 512 * 512);
    conv_bf16<<<dim3(256),   blk, 0, stream>>>(Wl,   Wlb,  512 * 512);
    conv_bf16<<<dim3(128),   blk, 0, stream>>>(Wdp,  Wdpb, 256 * 512);
    transpose_wexp<<<dim3(4096), blk, 0, stream>>>(W_exp, WexpT);
    transpose_whead<<<dim3(1024), blk, 0, stream>>>(W_head, WheadT);

    // ---- projections (MFMA) ----
    gemm_mfma<0><<<dim3(4, 24), blk, 0, stream>>>(
        xdb, Wdb, bd, nullptr, xd_bf, nullptr, NDIS, 512, 256, 0, 0, 0, 0);
    gemm_mfma<0><<<dim3(4, 313), blk, 0, stream>>>(
        xrb, Wprb, bp_r, nullptr, hr0b, nullptr, NRNA, 512, 512, 0, 0, 0, 0);
    gemm_mfma<0><<<dim3(4, 24), blk, 0, stream>>>(
        xd_bf, Wpdb, bp_d, nullptr, hd0b, nullptr, NDIS, 512, 512, 0, 0, 0, 0);

    // ---- attention dots ----
    dot_heads_bf<<<dim3((NRNA * 8) / 256), blk, 0, stream>>>(hr0b, a_src_rd, as_rd, NRNA);
    dot_heads_bf<<<dim3((NDIS * 8 + 255) / 256), blk, 0, stream>>>(hd0b, a_dst_rd, ad_rd, NDIS);
    dot_heads_bf<<<dim3((NDIS * 8 + 255) / 256), blk, 0, stream>>>(hd0b, a_src_dr, as_dr, NDIS);
    dot_heads_bf<<<dim3((NRNA * 8) / 256), blk, 0, stream>>>(hr0b, a_dst_dr, ad_dr, NRNA);

    // ---- CSR ----
    hipMemsetAsync(deg_rd, 0, NDIS * 4, stream);
    hipMemsetAsync(deg_dr, 0, NRNA * 4, stream);
    hist_kernel<<<dim3((NEDG + 255) / 256), blk, 0, stream>>>(ei_rd_dst, deg_rd, NEDG);
    hist_kernel<<<dim3((NEDG + 255) / 256), blk, 0, stream>>>(ei_dr_dst, deg_dr, NEDG);
    exscan_kernel<<<1, 1024, 0, stream>>>(deg_rd, offs_rd, NDIS);
    exscan_kernel<<<1, 1024, 0, stream>>>(deg_dr, offs_dr, NRNA);
    hipMemcpyAsync(cur_rd, offs_rd, NDIS * 4, hipMemcpyDeviceToDevice, stream);
    hipMemcpyAsync(cur_dr, offs_dr, NRNA * 4, hipMemcpyDeviceToDevice, stream);
    scatter_kernel<<<dim3((NEDG + 255) / 256), blk, 0, stream>>>(ei_rd_src, ei_rd_dst, cur_rd, csr_rd, NEDG);
    scatter_kernel<<<dim3((NEDG + 255) / 256), blk, 0, stream>>>(ei_dr_src, ei_dr_dst, cur_dr, csr_dr, NEDG);

    // ---- HAN aggregation (bf16 out) ----
    han_aggregate<<<dim3(NDIS), blk, 0, stream>>>(offs_rd, csr_rd, as_rd, ad_rd, hr0b, outdis_b);
    han_aggregate<<<dim3(NRNA), blk, 0, stream>>>(offs_dr, csr_dr, as_dr, ad_dr, hd0b, outrna_b);

    // ---- final shared linear ----
    gemm_mfma<0><<<dim3(4, 313), blk, 0, stream>>>(
        outrna_b, Wlb, bl, nullptr, hrna_b, nullptr, NRNA, 512, 512, 0, 0, 0, 0);
    gemm_mfma<0><<<dim3(4, 24), blk, 0, stream>>>(
        outdis_b, Wlb, bl, hdis_f, hdis_b, nullptr, NDIS, 512, 512, 0, 0, 0, 0);

    // ---- d_global, folded expert bias, gate scores ----
    hdis_colsum_partial<<<dim3(15), dim3(512), 0, stream>>>(hdis_f, dg_part);
    hdis_colsum_finish<<<dim3(1), dim3(512), 0, stream>>>(dg_part, dg);
    cexp_kernel<<<dim3(8), blk, 0, stream>>>(dg, W_exp, b_exp, c_exp);
    scores_bf<<<dim3((4 * TREL * 8) / 256), blk, 0, stream>>>(hrna_b, W_gate, idx_rels, S);

    // ---- fused MoE (MFMA) ----
    moe_mfma<<<dim3(2, 313), blk, 0, stream>>>(hrna_b, WexpT, c_exp, S, idx_rels, u_bf);

    // ---- U mean, cross attention, folded head bias ----
    u_mean_partial<<<dim3(32, 4), blk, 0, stream>>>(u_bf, u_part);
    u_mean_finish<<<dim3(4), blk, 0, stream>>>(u_part, U);
    cross_attn_kernel<<<dim3(1), blk, 0, stream>>>(U, in_w, in_b, out_w, out_b, Up);
    chead_kernel<<<dim3(4), blk, 0, stream>>>(Up, W_head, b_head, c_head);

    // ---- per-relation heads (MFMA, relu, bf16 out) ----
    gemm_mfma<1><<<dim3(2, 79, 4), blk, 0, stream>>>(
        u_bf, WheadT, c_head, nullptr, p_bf, nullptr, TREL, 256, 256,
        (long)TREL * 256, 65536, 256, (long)TREL * 256);

    // ---- disease projection (MFMA, bf16 out) ----
    gemm_mfma<0><<<dim3(2, 24), blk, 0, stream>>>(
        hdis_b, Wdpb, bdp, nullptr, dproj_b, nullptr, NDIS, 256, 512, 0, 0, 0, 0);

    // ---- final scores: sigmoid(p @ d_proj^T) ----
    gemm_mfma<2><<<dim3(24, 313), blk, 0, stream>>>(
        p_bf, dproj_b, nullptr, out, nullptr, nullptr, 4 * TREL, NDIS, 256, 0, 0, 0, 0);
}